// Round 2
// baseline (603.789 us; speedup 1.0000x reference)
//
#include <hip/hip_runtime.h>

#define HH 8
#define LL 256
#define CC 32
#define VT_STRIDE 264   // padded sk2 stride for V^T, multiple of 8 (b128 align)
#define PC_STRIDE 40    // per-wave P chunk stride, multiple of 8 (b128 align)

typedef _Float16 f16x8 __attribute__((ext_vector_type(8)));
typedef _Float16 f16x4 __attribute__((ext_vector_type(4)));
typedef float    f32x4 __attribute__((ext_vector_type(4)));

// Transpose bias (B=1, s2, sk2, H) -> biasT [H][s2][sk2] so the main kernel's
// bias loads become lane-coalesced float4.
__global__ __launch_bounds__(256)
void bias_transpose(const float* __restrict__ bias, float* __restrict__ biasT) {
    const int g = blockIdx.x * 256 + threadIdx.x;   // g = h*65536 + s2*256 + sk2
    const int h = g >> 16;
    const int s2sk2 = g & 65535;
    biasT[g] = bias[(s2sk2 << 3) | h];
}

__global__ __launch_bounds__(256, 4)
void triattn(const float* __restrict__ q, const float* __restrict__ k,
             const float* __restrict__ v, const float* __restrict__ bias,
             const float* __restrict__ biasT,   // may be null -> fallback path
             const float* __restrict__ gate, float* __restrict__ out) {
    __shared__ _Float16 Klds[LL * CC];            // [sk2][32]      16384 B
    __shared__ _Float16 Vt[CC * VT_STRIDE];       // [c][sk2]       16896 B
    __shared__ _Float16 Pc[4][16 * PC_STRIDE];    // per-wave chunk  5120 B

    const int h    = blockIdx.y;
    const int s1   = blockIdx.x;
    const int tid  = threadIdx.x;
    const int wave = tid >> 6;
    const int lane = tid & 63;
    const int n16  = lane & 15;
    const int quad = lane >> 4;

    const size_t base = ((size_t)(h * LL + s1)) * (LL * CC);
    const float* qb = q + base;
    const float* kb = k + base;
    const float* vb = v + base;
    float*       ob = out + base;
    const float* gateb = gate + ((size_t)s1 * (LL * CC * HH)) + h;

    // ---- stage K and V^T into LDS as fp16 ----
    const float4* k4 = (const float4*)kb;
    const float4* v4 = (const float4*)vb;
    #pragma unroll
    for (int i = 0; i < 8; ++i) {
        const int idx = tid + i * 256;        // float4 index over 2048
        const int row = idx >> 3;             // sk2
        const int c0  = (idx & 7) * 4;        // channel base
        float4 f = k4[idx];
        f16x4 kv4 = { (_Float16)f.x, (_Float16)f.y, (_Float16)f.z, (_Float16)f.w };
        *(f16x4*)&Klds[row * CC + c0] = kv4;
        float4 g = v4[idx];
        _Float16* vd = &Vt[c0 * VT_STRIDE + row];
        vd[0]             = (_Float16)g.x;
        vd[VT_STRIDE]     = (_Float16)g.y;
        vd[2 * VT_STRIDE] = (_Float16)g.z;
        vd[3 * VT_STRIDE] = (_Float16)g.w;
    }
    __syncthreads();

    _Float16* pw = Pc[wave];

    #pragma unroll 1
    for (int si = 0; si < 4; ++si) {
        const int strip = wave * 4 + si;
        const int r0 = strip * 16;            // s2 base for this strip

        // hoisted gate loads (consumed in epilogue; latency hidden under compute)
        float gv0[4], gv1[4];
        #pragma unroll
        for (int r = 0; r < 4; ++r) {
            const int s2 = r0 + quad * 4 + r;
            gv0[r] = gateb[(s2 * CC + n16) * HH];
            gv1[r] = gateb[(s2 * CC + 16 + n16) * HH];
        }

        // Q as B-operand fragment: B[k=c=quad*8+j][n=s2=n16]
        f16x8 qf;
        {
            const float4* qr4 = (const float4*)(qb + (size_t)(r0 + n16) * CC + quad * 8);
            float4 a = qr4[0], b = qr4[1];
            qf[0] = (_Float16)a.x; qf[1] = (_Float16)a.y;
            qf[2] = (_Float16)a.z; qf[3] = (_Float16)a.w;
            qf[4] = (_Float16)b.x; qf[5] = (_Float16)b.y;
            qf[6] = (_Float16)b.z; qf[7] = (_Float16)b.w;
        }

        // ---- S^T = K · Q^T : acc[t] row = sk2 = t*16+quad*4+r, col = s2 = n16 ----
        f32x4 acc[16];
        #pragma unroll
        for (int t = 0; t < 16; ++t) {
            f16x8 kf = *(const f16x8*)&Klds[(t * 16 + n16) * CC + quad * 8];
            f32x4 z = {0.f, 0.f, 0.f, 0.f};
            acc[t] = __builtin_amdgcn_mfma_f32_16x16x32_f16(kf, qf, z, 0, 0, 0);
        }

        // ---- bias add: bias[s2 = r0+n16][sk2 = t*16+quad*4+r] ----
        if (biasT) {
            const float4* bb = (const float4*)(biasT + ((size_t)h << 16)
                                               + (size_t)(r0 + n16) * LL) + quad;
            #pragma unroll
            for (int t = 0; t < 16; ++t) {
                float4 bv = bb[t * 4];
                acc[t][0] += bv.x; acc[t][1] += bv.y;
                acc[t][2] += bv.z; acc[t][3] += bv.w;
            }
        } else {
            const float* bb = bias + h + ((size_t)(r0 + n16) * LL + quad * 4) * HH;
            #pragma unroll
            for (int t = 0; t < 16; ++t)
                #pragma unroll
                for (int r = 0; r < 4; ++r)
                    acc[t][r] += bb[(t * 16 + r) * HH];
        }

        // ---- softmax over sk2: 64 in-lane values + 2 cross-quad shuffles ----
        f32x4 mv = acc[0];
        #pragma unroll
        for (int t = 1; t < 16; ++t) {
            mv[0] = fmaxf(mv[0], acc[t][0]); mv[1] = fmaxf(mv[1], acc[t][1]);
            mv[2] = fmaxf(mv[2], acc[t][2]); mv[3] = fmaxf(mv[3], acc[t][3]);
        }
        float m = fmaxf(fmaxf(mv[0], mv[1]), fmaxf(mv[2], mv[3]));
        m = fmaxf(m, __shfl_xor(m, 16));
        m = fmaxf(m, __shfl_xor(m, 32));

        f32x4 sv = {0.f, 0.f, 0.f, 0.f};
        #pragma unroll
        for (int t = 0; t < 16; ++t) {
            #pragma unroll
            for (int r = 0; r < 4; ++r) {
                float p = exp2f((acc[t][r] - m) * 1.44269504f);
                acc[t][r] = p;
                sv[r] += p;
            }
        }
        float s = (sv[0] + sv[1]) + (sv[2] + sv[3]);
        s += __shfl_xor(s, 16);
        s += __shfl_xor(s, 32);
        const float inv = 1.f / s;   // per s2-row (indexed by n16); applied post-PV

        // ---- O = P̂·V, P̂ routed through small per-wave LDS chunk per kk ----
        f32x4 o0 = {0.f, 0.f, 0.f, 0.f}, o1 = {0.f, 0.f, 0.f, 0.f};
        #pragma unroll
        for (int kk = 0; kk < 8; ++kk) {
            const int t0 = 2 * kk, t1 = 2 * kk + 1;
            f16x4 pa = { (_Float16)acc[t0][0], (_Float16)acc[t0][1],
                         (_Float16)acc[t0][2], (_Float16)acc[t0][3] };
            f16x4 pb = { (_Float16)acc[t1][0], (_Float16)acc[t1][1],
                         (_Float16)acc[t1][2], (_Float16)acc[t1][3] };
            *(f16x4*)&pw[n16 * PC_STRIDE + quad * 4]      = pa;  // sk2_local quad*4..+3
            *(f16x4*)&pw[n16 * PC_STRIDE + 16 + quad * 4] = pb;  // sk2_local 16+quad*4..+3
            // same-wave DS ops are in-order: read below sees this kk's data,
            // and next kk's overwrite cannot pass this kk's read.
            f16x8 pf  = *(const f16x8*)&pw[n16 * PC_STRIDE + quad * 8];
            f16x8 vf0 = *(const f16x8*)&Vt[n16 * VT_STRIDE + kk * 32 + quad * 8];
            f16x8 vf1 = *(const f16x8*)&Vt[(16 + n16) * VT_STRIDE + kk * 32 + quad * 8];
            o0 = __builtin_amdgcn_mfma_f32_16x16x32_f16(pf, vf0, o0, 0, 0, 0);
            o1 = __builtin_amdgcn_mfma_f32_16x16x32_f16(pf, vf1, o1, 0, 0, 0);
        }

        // ---- epilogue: normalize (shuffled inv), gate, store ----
        #pragma unroll
        for (int r = 0; r < 4; ++r) {
            const float wr = __shfl(inv, quad * 4 + r);   // inv for s2-row quad*4+r
            const int s2 = r0 + quad * 4 + r;
            ob[(size_t)s2 * CC + n16]      = o0[r] * wr * gv0[r];
            ob[(size_t)s2 * CC + 16 + n16] = o1[r] * wr * gv1[r];
        }
    }
}

extern "C" void kernel_launch(void* const* d_in, const int* in_sizes, int n_in,
                              void* d_out, int out_size, void* d_ws, size_t ws_size,
                              hipStream_t stream) {
    const float* q    = (const float*)d_in[0];
    const float* k    = (const float*)d_in[1];
    const float* v    = (const float*)d_in[2];
    const float* bias = (const float*)d_in[3];
    const float* gate = (const float*)d_in[4];
    float* out = (float*)d_out;

    float* biasT = nullptr;
    if (ws_size >= (size_t)HH * LL * LL * sizeof(float)) {
        biasT = (float*)d_ws;
        bias_transpose<<<dim3((HH * LL * LL) / 256), 256, 0, stream>>>(bias, biasT);
    }
    dim3 grid(LL, HH);
    triattn<<<grid, 256, 0, stream>>>(q, k, v, bias, biasT, gate, out);
}

// Round 3
// 520.688 us; speedup vs baseline: 1.1596x; 1.1596x over previous
//
#include <hip/hip_runtime.h>

#define HH 8
#define LL 256
#define CC 32
#define VT_STRIDE 264   // padded sk2 stride for V^T, multiple of 8 (b128 align)
#define PC_STRIDE 40    // per-wave P chunk stride, multiple of 8 (b128 align)

typedef _Float16 f16x8 __attribute__((ext_vector_type(8)));
typedef _Float16 f16x4 __attribute__((ext_vector_type(4)));
typedef float    f32x4 __attribute__((ext_vector_type(4)));

// Transpose bias (B=1, s2, sk2, H) -> biasT [H][s2][sk2] so the main kernel's
// bias loads become lane-coalesced float4.
__global__ __launch_bounds__(256)
void bias_transpose(const float* __restrict__ bias, float* __restrict__ biasT) {
    const int g = blockIdx.x * 256 + threadIdx.x;   // g = h*65536 + s2*256 + sk2
    const int h = g >> 16;
    const int s2sk2 = g & 65535;
    biasT[g] = bias[(s2sk2 << 3) | h];
}

// (256, 3): VGPR cap = 512/3 = 170 — kernel needs ~125 live regs (acc[16] is
// 64 f32 across softmax). (256, 4) capped at 128 and spilled ~1.3 GB/dispatch
// to scratch (round-2 counters: WRITE_SIZE 565 MB). LDS 38.4 KB also allows
// 3 blocks/CU, so 3 waves/EU is the spill-free occupancy sweet spot.
__global__ __launch_bounds__(256, 3)
void triattn(const float* __restrict__ q, const float* __restrict__ k,
             const float* __restrict__ v, const float* __restrict__ bias,
             const float* __restrict__ biasT,   // may be null -> fallback path
             const float* __restrict__ gate, float* __restrict__ out) {
    __shared__ _Float16 Klds[LL * CC];            // [sk2][32]      16384 B
    __shared__ _Float16 Vt[CC * VT_STRIDE];       // [c][sk2]       16896 B
    __shared__ _Float16 Pc[4][16 * PC_STRIDE];    // per-wave chunk  5120 B

    const int h    = blockIdx.y;
    const int s1   = blockIdx.x;
    const int tid  = threadIdx.x;
    const int wave = tid >> 6;
    const int lane = tid & 63;
    const int n16  = lane & 15;
    const int quad = lane >> 4;

    const size_t base = ((size_t)(h * LL + s1)) * (LL * CC);
    const float* qb = q + base;
    const float* kb = k + base;
    const float* vb = v + base;
    float*       ob = out + base;
    const float* gateb = gate + ((size_t)s1 * (LL * CC * HH)) + h;

    // ---- stage K and V^T into LDS as fp16 ----
    const float4* k4 = (const float4*)kb;
    const float4* v4 = (const float4*)vb;
    #pragma unroll
    for (int i = 0; i < 8; ++i) {
        const int idx = tid + i * 256;        // float4 index over 2048
        const int row = idx >> 3;             // sk2
        const int c0  = (idx & 7) * 4;        // channel base
        float4 f = k4[idx];
        f16x4 kv4 = { (_Float16)f.x, (_Float16)f.y, (_Float16)f.z, (_Float16)f.w };
        *(f16x4*)&Klds[row * CC + c0] = kv4;
        float4 g = v4[idx];
        _Float16* vd = &Vt[c0 * VT_STRIDE + row];
        vd[0]             = (_Float16)g.x;
        vd[VT_STRIDE]     = (_Float16)g.y;
        vd[2 * VT_STRIDE] = (_Float16)g.z;
        vd[3 * VT_STRIDE] = (_Float16)g.w;
    }
    __syncthreads();

    _Float16* pw = Pc[wave];

    #pragma unroll 1
    for (int si = 0; si < 4; ++si) {
        const int strip = wave * 4 + si;
        const int r0 = strip * 16;            // s2 base for this strip

        // Q as B-operand fragment: B[k=c=quad*8+j][n=s2=n16]
        f16x8 qf;
        {
            const float4* qr4 = (const float4*)(qb + (size_t)(r0 + n16) * CC + quad * 8);
            float4 a = qr4[0], b = qr4[1];
            qf[0] = (_Float16)a.x; qf[1] = (_Float16)a.y;
            qf[2] = (_Float16)a.z; qf[3] = (_Float16)a.w;
            qf[4] = (_Float16)b.x; qf[5] = (_Float16)b.y;
            qf[6] = (_Float16)b.z; qf[7] = (_Float16)b.w;
        }

        // ---- S^T = K · Q^T : acc[t] row = sk2 = t*16+quad*4+r, col = s2 = n16 ----
        f32x4 acc[16];
        #pragma unroll
        for (int t = 0; t < 16; ++t) {
            f16x8 kf = *(const f16x8*)&Klds[(t * 16 + n16) * CC + quad * 8];
            f32x4 z = {0.f, 0.f, 0.f, 0.f};
            acc[t] = __builtin_amdgcn_mfma_f32_16x16x32_f16(kf, qf, z, 0, 0, 0);
        }

        // ---- bias add: bias[s2 = r0+n16][sk2 = t*16+quad*4+r] ----
        if (biasT) {
            const float4* bb = (const float4*)(biasT + ((size_t)h << 16)
                                               + (size_t)(r0 + n16) * LL) + quad;
            #pragma unroll
            for (int t = 0; t < 16; ++t) {
                float4 bv = bb[t * 4];
                acc[t][0] += bv.x; acc[t][1] += bv.y;
                acc[t][2] += bv.z; acc[t][3] += bv.w;
            }
        } else {
            const float* bb = bias + h + ((size_t)(r0 + n16) * LL + quad * 4) * HH;
            #pragma unroll
            for (int t = 0; t < 16; ++t)
                #pragma unroll
                for (int r = 0; r < 4; ++r)
                    acc[t][r] += bb[(t * 16 + r) * HH];
        }

        // ---- softmax over sk2: 64 in-lane values + 2 cross-quad shuffles ----
        f32x4 mv = acc[0];
        #pragma unroll
        for (int t = 1; t < 16; ++t) {
            mv[0] = fmaxf(mv[0], acc[t][0]); mv[1] = fmaxf(mv[1], acc[t][1]);
            mv[2] = fmaxf(mv[2], acc[t][2]); mv[3] = fmaxf(mv[3], acc[t][3]);
        }
        float m = fmaxf(fmaxf(mv[0], mv[1]), fmaxf(mv[2], mv[3]));
        m = fmaxf(m, __shfl_xor(m, 16));
        m = fmaxf(m, __shfl_xor(m, 32));

        f32x4 sv = {0.f, 0.f, 0.f, 0.f};
        #pragma unroll
        for (int t = 0; t < 16; ++t) {
            #pragma unroll
            for (int r = 0; r < 4; ++r) {
                float p = exp2f((acc[t][r] - m) * 1.44269504f);
                acc[t][r] = p;
                sv[r] += p;
            }
        }
        float s = (sv[0] + sv[1]) + (sv[2] + sv[3]);
        s += __shfl_xor(s, 16);
        s += __shfl_xor(s, 32);
        const float inv = 1.f / s;   // per s2-row (indexed by n16); applied post-PV

        // ---- O = P̂·V, P̂ routed through small per-wave LDS chunk per kk ----
        f32x4 o0 = {0.f, 0.f, 0.f, 0.f}, o1 = {0.f, 0.f, 0.f, 0.f};
        #pragma unroll
        for (int kk = 0; kk < 8; ++kk) {
            const int t0 = 2 * kk, t1 = 2 * kk + 1;
            f16x4 pa = { (_Float16)acc[t0][0], (_Float16)acc[t0][1],
                         (_Float16)acc[t0][2], (_Float16)acc[t0][3] };
            f16x4 pb = { (_Float16)acc[t1][0], (_Float16)acc[t1][1],
                         (_Float16)acc[t1][2], (_Float16)acc[t1][3] };
            *(f16x4*)&pw[n16 * PC_STRIDE + quad * 4]      = pa;  // sk2_local quad*4..+3
            *(f16x4*)&pw[n16 * PC_STRIDE + 16 + quad * 4] = pb;  // sk2_local 16+quad*4..+3
            // same-wave DS ops are in-order: read below sees this kk's data,
            // and next kk's overwrite cannot pass this kk's read.
            f16x8 pf  = *(const f16x8*)&pw[n16 * PC_STRIDE + quad * 8];
            f16x8 vf0 = *(const f16x8*)&Vt[n16 * VT_STRIDE + kk * 32 + quad * 8];
            f16x8 vf1 = *(const f16x8*)&Vt[(16 + n16) * VT_STRIDE + kk * 32 + quad * 8];
            o0 = __builtin_amdgcn_mfma_f32_16x16x32_f16(pf, vf0, o0, 0, 0, 0);
            o1 = __builtin_amdgcn_mfma_f32_16x16x32_f16(pf, vf1, o1, 0, 0, 0);
        }

        // ---- epilogue: normalize (shuffled inv), gate, store ----
        #pragma unroll
        for (int r = 0; r < 4; ++r) {
            const float wr = __shfl(inv, quad * 4 + r);   // inv for s2-row quad*4+r
            const int s2 = r0 + quad * 4 + r;
            const float g0 = gateb[(s2 * CC + n16) * HH];
            const float g1 = gateb[(s2 * CC + 16 + n16) * HH];
            ob[(size_t)s2 * CC + n16]      = o0[r] * wr * g0;
            ob[(size_t)s2 * CC + 16 + n16] = o1[r] * wr * g1;
        }
    }
}

extern "C" void kernel_launch(void* const* d_in, const int* in_sizes, int n_in,
                              void* d_out, int out_size, void* d_ws, size_t ws_size,
                              hipStream_t stream) {
    const float* q    = (const float*)d_in[0];
    const float* k    = (const float*)d_in[1];
    const float* v    = (const float*)d_in[2];
    const float* bias = (const float*)d_in[3];
    const float* gate = (const float*)d_in[4];
    float* out = (float*)d_out;

    float* biasT = nullptr;
    if (ws_size >= (size_t)HH * LL * LL * sizeof(float)) {
        biasT = (float*)d_ws;
        bias_transpose<<<dim3((HH * LL * LL) / 256), 256, 0, stream>>>(bias, biasT);
    }
    dim3 grid(LL, HH);
    triattn<<<grid, 256, 0, stream>>>(q, k, v, bias, biasT, gate, out);
}

// Round 4
// 488.545 us; speedup vs baseline: 1.2359x; 1.0658x over previous
//
#include <hip/hip_runtime.h>

#define HH 8
#define LL 256
#define CC 32
#define VT_STRIDE 264   // padded sk2 stride for V^T, multiple of 8 (b128 align)
#define PC_STRIDE 40    // per-wave P chunk stride, multiple of 8 (b128 align)

typedef _Float16 f16x8 __attribute__((ext_vector_type(8)));
typedef _Float16 f16x4 __attribute__((ext_vector_type(4)));
typedef float    f32x4 __attribute__((ext_vector_type(4)));

// Transpose bias (B=1, s2, sk2, H) -> biasT [H][s2][sk2] so the main kernel's
// bias loads become lane-coalesced float4.
__global__ __launch_bounds__(256)
void bias_transpose(const float* __restrict__ bias, float* __restrict__ biasT) {
    const int g = blockIdx.x * 256 + threadIdx.x;   // g = h*65536 + s2*256 + sk2
    const int h = g >> 16;
    const int s2sk2 = g & 65535;
    biasT[g] = bias[(s2sk2 << 3) | h];
}

// Flash-split over sk2 (two 128-wide halves, online softmax) so only 8 f32x4
// score regs are live at once (~70 regs total). Rounds 2-3 kept all 16 tiles
// (64 f32) live across softmax and spilled 0.3-1.3 GB/dispatch to scratch
// (FETCH/WRITE counters). (256,4): cap 128 regs, 4 blocks/CU at 38.4 KB LDS.
__global__ __launch_bounds__(256, 4)
void triattn(const float* __restrict__ q, const float* __restrict__ k,
             const float* __restrict__ v, const float* __restrict__ bias,
             const float* __restrict__ biasT,   // may be null -> fallback path
             const float* __restrict__ gate, float* __restrict__ out) {
    __shared__ _Float16 Klds[LL * CC];            // [sk2][32]      16384 B
    __shared__ _Float16 Vt[CC * VT_STRIDE];       // [c][sk2]       16896 B
    __shared__ _Float16 Pc[4][16 * PC_STRIDE];    // per-wave chunk  5120 B

    const int h    = blockIdx.y;
    const int s1   = blockIdx.x;
    const int tid  = threadIdx.x;
    const int wave = tid >> 6;
    const int lane = tid & 63;
    const int n16  = lane & 15;
    const int quad = lane >> 4;

    const size_t base = ((size_t)(h * LL + s1)) * (LL * CC);
    const float* qb = q + base;
    const float* kb = k + base;
    const float* vb = v + base;
    float*       ob = out + base;
    const float* gateb = gate + ((size_t)s1 * (LL * CC * HH)) + h;

    // ---- stage K and V^T into LDS as fp16 ----
    const float4* k4 = (const float4*)kb;
    const float4* v4 = (const float4*)vb;
    #pragma unroll
    for (int i = 0; i < 8; ++i) {
        const int idx = tid + i * 256;        // float4 index over 2048
        const int row = idx >> 3;             // sk2
        const int c0  = (idx & 7) * 4;        // channel base
        float4 f = k4[idx];
        f16x4 kv4 = { (_Float16)f.x, (_Float16)f.y, (_Float16)f.z, (_Float16)f.w };
        *(f16x4*)&Klds[row * CC + c0] = kv4;
        float4 g = v4[idx];
        _Float16* vd = &Vt[c0 * VT_STRIDE + row];
        vd[0]             = (_Float16)g.x;
        vd[VT_STRIDE]     = (_Float16)g.y;
        vd[2 * VT_STRIDE] = (_Float16)g.z;
        vd[3 * VT_STRIDE] = (_Float16)g.w;
    }
    __syncthreads();

    _Float16* pw = Pc[wave];

    #pragma unroll 1
    for (int si = 0; si < 4; ++si) {
        const int strip = wave * 4 + si;
        const int r0 = strip * 16;            // s2 base for this strip

        // Q as B-operand fragment: B[k=c=quad*8+j][n=s2=n16]
        f16x8 qf;
        {
            const float4* qr4 = (const float4*)(qb + (size_t)(r0 + n16) * CC + quad * 8);
            float4 a = qr4[0], b = qr4[1];
            qf[0] = (_Float16)a.x; qf[1] = (_Float16)a.y;
            qf[2] = (_Float16)a.z; qf[3] = (_Float16)a.w;
            qf[4] = (_Float16)b.x; qf[5] = (_Float16)b.y;
            qf[6] = (_Float16)b.z; qf[7] = (_Float16)b.w;
        }

        f32x4 o0 = {0.f, 0.f, 0.f, 0.f}, o1 = {0.f, 0.f, 0.f, 0.f};
        float mrow = 0.f;   // valid after hh=0
        float srow = 0.f;

        #pragma unroll
        for (int hh = 0; hh < 2; ++hh) {
            // ---- S^T half: acc[t] row = sk2 = (hh*8+t)*16+quad*4+r, col = s2 = n16 ----
            f32x4 acc[8];
            #pragma unroll
            for (int t = 0; t < 8; ++t) {
                f16x8 kf = *(const f16x8*)&Klds[((hh * 8 + t) * 16 + n16) * CC + quad * 8];
                f32x4 z = {0.f, 0.f, 0.f, 0.f};
                acc[t] = __builtin_amdgcn_mfma_f32_16x16x32_f16(kf, qf, z, 0, 0, 0);
            }

            // ---- bias add: bias[s2 = r0+n16][sk2 = (hh*8+t)*16+quad*4+r] ----
            if (biasT) {
                const float4* bb = (const float4*)(biasT + ((size_t)h << 16)
                                                   + (size_t)(r0 + n16) * LL) + quad;
                #pragma unroll
                for (int t = 0; t < 8; ++t) {
                    float4 bv = bb[(hh * 8 + t) * 4];
                    acc[t][0] += bv.x; acc[t][1] += bv.y;
                    acc[t][2] += bv.z; acc[t][3] += bv.w;
                }
            } else {
                const float* bb = bias + h + ((size_t)(r0 + n16) * LL + quad * 4) * HH;
                #pragma unroll
                for (int t = 0; t < 8; ++t)
                    #pragma unroll
                    for (int r = 0; r < 4; ++r)
                        acc[t][r] += bb[((hh * 8 + t) * 16 + r) * HH];
            }

            // ---- local row-max (rows = s2 = n16; quad-uniform after shuffles) ----
            f32x4 mv = acc[0];
            #pragma unroll
            for (int t = 1; t < 8; ++t) {
                mv[0] = fmaxf(mv[0], acc[t][0]); mv[1] = fmaxf(mv[1], acc[t][1]);
                mv[2] = fmaxf(mv[2], acc[t][2]); mv[3] = fmaxf(mv[3], acc[t][3]);
            }
            float ml = fmaxf(fmaxf(mv[0], mv[1]), fmaxf(mv[2], mv[3]));
            ml = fmaxf(ml, __shfl_xor(ml, 16));
            ml = fmaxf(ml, __shfl_xor(ml, 32));

            const float mNew = (hh == 0) ? ml : fmaxf(mrow, ml);

            // ---- exp + local sum ----
            f32x4 sv = {0.f, 0.f, 0.f, 0.f};
            #pragma unroll
            for (int t = 0; t < 8; ++t) {
                #pragma unroll
                for (int r = 0; r < 4; ++r) {
                    float p = exp2f((acc[t][r] - mNew) * 1.44269504f);
                    acc[t][r] = p;
                    sv[r] += p;
                }
            }
            float sl = (sv[0] + sv[1]) + (sv[2] + sv[3]);
            sl += __shfl_xor(sl, 16);
            sl += __shfl_xor(sl, 32);

            if (hh == 0) {
                srow = sl;
            } else {
                const float alpha = exp2f((mrow - mNew) * 1.44269504f);
                srow = srow * alpha + sl;
                // rescale o BEFORE accumulating this half's PV
                #pragma unroll
                for (int r = 0; r < 4; ++r) {
                    const float ar = __shfl(alpha, quad * 4 + r);
                    o0[r] *= ar; o1[r] *= ar;
                }
            }
            mrow = mNew;

            // ---- PV for this half: kk chunks of 32 sk2 ----
            #pragma unroll
            for (int kl = 0; kl < 4; ++kl) {
                const int kg = hh * 4 + kl;
                const int t0 = 2 * kl, t1 = 2 * kl + 1;
                f16x4 pa = { (_Float16)acc[t0][0], (_Float16)acc[t0][1],
                             (_Float16)acc[t0][2], (_Float16)acc[t0][3] };
                f16x4 pb = { (_Float16)acc[t1][0], (_Float16)acc[t1][1],
                             (_Float16)acc[t1][2], (_Float16)acc[t1][3] };
                *(f16x4*)&pw[n16 * PC_STRIDE + quad * 4]      = pa;
                *(f16x4*)&pw[n16 * PC_STRIDE + 16 + quad * 4] = pb;
                // same-wave DS ops are in-order: read sees this chunk's data,
                // and the next chunk's overwrite cannot pass this read.
                f16x8 pf  = *(const f16x8*)&pw[n16 * PC_STRIDE + quad * 8];
                f16x8 vf0 = *(const f16x8*)&Vt[n16 * VT_STRIDE + kg * 32 + quad * 8];
                f16x8 vf1 = *(const f16x8*)&Vt[(16 + n16) * VT_STRIDE + kg * 32 + quad * 8];
                o0 = __builtin_amdgcn_mfma_f32_16x16x32_f16(pf, vf0, o0, 0, 0, 0);
                o1 = __builtin_amdgcn_mfma_f32_16x16x32_f16(pf, vf1, o1, 0, 0, 0);
            }
        }

        // ---- epilogue: normalize (shuffled inv), gate, store ----
        const float inv = 1.f / srow;   // per s2-row (indexed by n16)
        #pragma unroll
        for (int r = 0; r < 4; ++r) {
            const float wr = __shfl(inv, quad * 4 + r);
            const int s2 = r0 + quad * 4 + r;
            const float g0 = gateb[(s2 * CC + n16) * HH];
            const float g1 = gateb[(s2 * CC + 16 + n16) * HH];
            ob[(size_t)s2 * CC + n16]      = o0[r] * wr * g0;
            ob[(size_t)s2 * CC + 16 + n16] = o1[r] * wr * g1;
        }
    }
}

extern "C" void kernel_launch(void* const* d_in, const int* in_sizes, int n_in,
                              void* d_out, int out_size, void* d_ws, size_t ws_size,
                              hipStream_t stream) {
    const float* q    = (const float*)d_in[0];
    const float* k    = (const float*)d_in[1];
    const float* v    = (const float*)d_in[2];
    const float* bias = (const float*)d_in[3];
    const float* gate = (const float*)d_in[4];
    float* out = (float*)d_out;

    float* biasT = nullptr;
    if (ws_size >= (size_t)HH * LL * LL * sizeof(float)) {
        biasT = (float*)d_ws;
        bias_transpose<<<dim3((HH * LL * LL) / 256), 256, 0, stream>>>(bias, biasT);
    }
    dim3 grid(LL, HH);
    triattn<<<grid, 256, 0, stream>>>(q, k, v, bias, biasT, gate, out);
}